// Round 25
// baseline (148.052 us; speedup 1.0000x reference)
//
#include <hip/hip_runtime.h>
#include <stdint.h>

typedef float  f32x4  __attribute__((ext_vector_type(4)));
typedef short  s16x4  __attribute__((ext_vector_type(4)));
typedef short  s16x8  __attribute__((ext_vector_type(8)));

#define S_LEN 2048
#define D_K   64
#define NBH   32
#define VT_STRIDE (S_LEN + 32)
#define MFMA  __builtin_amdgcn_mfma_f32_16x16x32_bf16

__device__ __forceinline__ short f2bf(float f) {
    uint32_t u = __builtin_bit_cast(uint32_t, f);
    u += 0x7fffu + ((u >> 16) & 1u);           // RNE
    return (short)(u >> 16);
}
__device__ __forceinline__ float bf2f(short s) {
    uint32_t u = ((uint32_t)(uint16_t)s) << 16;
    return __builtin_bit_cast(float, u);
}
__device__ __forceinline__ s16x4 cvt4(float4 f) {
    s16x4 r; r[0] = f2bf(f.x); r[1] = f2bf(f.y); r[2] = f2bf(f.z); r[3] = f2bf(f.w);
    return r;
}
__device__ __forceinline__ s16x8 cat(s16x4 a, s16x4 b) {
    return __builtin_shufflevector(a, b, 0, 1, 2, 3, 4, 5, 6, 7);
}
__device__ __forceinline__ void nt_store4(float* p, f32x4 v) {
    __builtin_nontemporal_store(v, (f32x4*)p);
}

// ---- pre-pass: K -> bf16 FRAG-PERMUTED rows, V -> bf16 transposed, k-permuted ----
__global__ __launch_bounds__(256) void preconv(
    const float* __restrict__ K, const float* __restrict__ V,
    short* __restrict__ Kb, short* __restrict__ VT)
{
    const int bh  = blockIdx.x >> 6;
    const int seg = blockIdx.x & 63;
    const int tid = threadIdx.x;
    const float* Ks = K + ((size_t)bh * S_LEN + seg * 32) * D_K;
    const float* Vs = V + ((size_t)bh * S_LEN + seg * 32) * D_K;
    short* Kd  = Kb + ((size_t)bh * S_LEN + seg * 32) * D_K;
    short* VTd = VT + (size_t)bh * D_K * VT_STRIDE + seg * 32;

    for (int i = tid; i < 512; i += 256) {
        const int r = i >> 4, ci = i & 15;
        float4 f = *(const float4*)(Ks + r * D_K + (ci << 2));
        const int jj = ((ci & 3) << 1) + ((ci >> 2) & 1) + ((ci >> 3) << 3);
        *(s16x4*)(Kd + r * D_K + (jj << 2)) = cvt4(f);
    }
    for (int i = tid; i < 512; i += 256) {
        const int r = i & 31, c = (i >> 5) << 2;
        float4 f = *(const float4*)(Vs + r * D_K + c);
        const int rp = (((r & 15) >> 2) << 3) + (((r >> 4) & 1) << 2) + (r & 3);
        VTd[(size_t)(c + 0) * VT_STRIDE + rp] = f2bf(f.x);
        VTd[(size_t)(c + 1) * VT_STRIDE + rp] = f2bf(f.y);
        VTd[(size_t)(c + 2) * VT_STRIDE + rp] = f2bf(f.z);
        VTd[(size_t)(c + 3) * VT_STRIDE + rp] = f2bf(f.w);
    }
}

// ---- single-pass pair kernel, 8 WAVES (2/SIMD TLP): ONE QK^T pass; bf16 exp
// ---- stash in 128KB LDS; unnormalized PV; 8KB/row mega-flush (fused zero-fill) ----
#define SSTR 2056    // shorts per stash row (2048 + 8 pad)
__global__ __launch_bounds__(512) void attn_sp8(
    const float* __restrict__ Q, const short* __restrict__ Kb,
    const short* __restrict__ VT, float* __restrict__ outC,
    float* __restrict__ outS)
{
    __shared__ __align__(16) char smem[32 * SSTR * 2];   // 131.6 KB stash / combine
    __shared__ float lbuf[8][32];

    const int tid = threadIdx.x, lane = tid & 63, wv = tid >> 6;   // 0..7
    const int xcd = blockIdx.x & 7;
    const int idx = blockIdx.x >> 3;             // 0..255
    const int bh  = (xcd << 2) + (idx >> 6);     // 0..31
    const int j   = 63 - (idx & 63);             // heavy pairs first
    const int q0  = j << 5;                      // strip a rows q0..+15, b rows +16..+31
    const int l15 = lane & 15;
    const int g   = lane >> 4;
    const int d0  = g << 2;
    const int qa  = q0 + l15;

    const short* Kbh = Kb + (size_t)bh * S_LEN * D_K;
    const short* VTh = VT + (size_t)bh * D_K * VT_STRIDE;
    float* outSb = outS + (size_t)bh * S_LEN * S_LEN;
    float* outCb = outC + (size_t)bh * S_LEN * D_K;
    short* sstash = (short*)smem;

    s16x8 qf0a, qf1a, qf0b, qf1b;
    {
        const float4* qp = (const float4*)(Q + ((size_t)bh * S_LEN + qa) * D_K);
        qf0a = cat(cvt4(qp[g]),     cvt4(qp[g + 4]));
        qf1a = cat(cvt4(qp[g + 8]), cvt4(qp[g + 12]));
        const float4* qp2 = (const float4*)(Q + ((size_t)bh * S_LEN + qa + 16) * D_K);
        qf0b = cat(cvt4(qp2[g]),     cvt4(qp2[g + 4]));
        qf1b = cat(cvt4(qp2[g + 8]), cvt4(qp2[g + 12]));
    }

    const int ntiles = j + 1;
    const float scale = 0.125f;

    // ============ single pass: QK^T -> exp (unnorm) -> stash + sums + PV ============
    float la = 0.f, lb = 0.f;
    f32x4 z4 = {0.f,0.f,0.f,0.f};
    f32x4 cxa0 = z4, cxa1 = z4, cxa2 = z4, cxa3 = z4;
    f32x4 cxb0 = z4, cxb1 = z4, cxb2 = z4, cxb3 = z4;
    {
        s16x8 k0[4], v0[4], k1[4], v1[4];

        auto LDK = [&](s16x8* kk, s16x8* vv, int t) {
            const short* kp = Kbh + (((size_t)t << 5) + l15) * D_K + (g << 3);
            kk[0] = *(const s16x8*)(kp);
            kk[1] = *(const s16x8*)(kp + 32);
            kk[2] = *(const s16x8*)(kp + 16 * D_K);
            kk[3] = *(const s16x8*)(kp + 16 * D_K + 32);
            const short* vp = VTh + (size_t)l15 * VT_STRIDE + (t << 5) + (g << 3);
            vv[0] = *(const s16x8*)(vp);
            vv[1] = *(const s16x8*)(vp + 16 * VT_STRIDE);
            vv[2] = *(const s16x8*)(vp + 32 * VT_STRIDE);
            vv[3] = *(const s16x8*)(vp + 48 * VT_STRIDE);
        };
        auto CMPS = [&](const s16x8* kk, const s16x8* vv, int T) {
            f32x4 sa0 = z4, sa1 = z4, sb0 = z4, sb1 = z4;
            sa0 = MFMA(kk[0], qf0a, sa0, 0,0,0);
            sa0 = MFMA(kk[1], qf1a, sa0, 0,0,0);
            sa1 = MFMA(kk[2], qf0a, sa1, 0,0,0);
            sa1 = MFMA(kk[3], qf1a, sa1, 0,0,0);
            sb0 = MFMA(kk[0], qf0b, sb0, 0,0,0);
            sb0 = MFMA(kk[1], qf1b, sb0, 0,0,0);
            sb1 = MFMA(kk[2], qf0b, sb1, 0,0,0);
            sb1 = MFMA(kk[3], qf1b, sb1, 0,0,0);
            s16x8 pfa, pfb;
            if (T < j) {
                #pragma unroll
                for (int r = 0; r < 4; ++r) {
                    float e;
                    e = __expf(sa0[r] * scale); la += e; pfa[r]   = f2bf(e);
                    e = __expf(sa1[r] * scale); la += e; pfa[4+r] = f2bf(e);
                    e = __expf(sb0[r] * scale); lb += e; pfb[r]   = f2bf(e);
                    e = __expf(sb1[r] * scale); lb += e; pfb[4+r] = f2bf(e);
                }
            } else {      // diagonal tile: a1 fully masked; shared lane condition
                #pragma unroll
                for (int r = 0; r < 4; ++r) {
                    const bool c = (d0 + r) <= l15;
                    float e;
                    e = c ? __expf(sa0[r] * scale) : 0.f; la += e; pfa[r] = f2bf(e);
                    pfa[4+r] = 0;
                    e = __expf(sb0[r] * scale);           lb += e; pfb[r] = f2bf(e);
                    e = c ? __expf(sb1[r] * scale) : 0.f; lb += e; pfb[4+r] = f2bf(e);
                }
            }
            // stash bf16 exp (unnormalized); wave-private tiles, no barrier needed
            const int cbase = (T << 5) + d0;
            short* sA = &sstash[l15 * SSTR + cbase];
            *(s16x4*)(sA)      = __builtin_shufflevector(pfa, pfa, 0, 1, 2, 3);
            *(s16x4*)(sA + 16) = __builtin_shufflevector(pfa, pfa, 4, 5, 6, 7);
            short* sB = &sstash[(16 + l15) * SSTR + cbase];
            *(s16x4*)(sB)      = __builtin_shufflevector(pfb, pfb, 0, 1, 2, 3);
            *(s16x4*)(sB + 16) = __builtin_shufflevector(pfb, pfb, 4, 5, 6, 7);
            cxa0 = MFMA(pfa, vv[0], cxa0, 0,0,0);
            cxa1 = MFMA(pfa, vv[1], cxa1, 0,0,0);
            cxa2 = MFMA(pfa, vv[2], cxa2, 0,0,0);
            cxa3 = MFMA(pfa, vv[3], cxa3, 0,0,0);
            cxb0 = MFMA(pfb, vv[0], cxb0, 0,0,0);
            cxb1 = MFMA(pfb, vv[1], cxb1, 0,0,0);
            cxb2 = MFMA(pfb, vv[2], cxb2, 0,0,0);
            cxb3 = MFMA(pfb, vv[3], cxb3, 0,0,0);
        };

        int t = wv;
        if (t < ntiles) {
            LDK(k0, v0, t);
            while (t + 8 < ntiles) {
                LDK(k1, v1, t + 8);
                CMPS(k0, v0, t);
                t += 8;
                if (t + 8 < ntiles) {
                    LDK(k0, v0, t + 8);
                    CMPS(k1, v1, t);
                    t += 8;
                } else {
                    CMPS(k1, v1, t);
                    t += 8;
                    break;
                }
            }
            if (t < ntiles) CMPS(k0, v0, t);
        }
    }
    la += __shfl_xor(la, 16); la += __shfl_xor(la, 32);
    lb += __shfl_xor(lb, 16); lb += __shfl_xor(lb, 32);
    if (lane < 16) { lbuf[wv][l15] = la; lbuf[wv][16 + l15] = lb; }
    __syncthreads();
    // ctx accumulator row is d0+r (C/D layout); sum over 8 waves
    #pragma unroll
    for (int r = 0; r < 4; ++r) {
        float sa = 0.f, sb = 0.f;
        #pragma unroll
        for (int w = 0; w < 8; ++w) {
            sa += lbuf[w][d0 + r];
            sb += lbuf[w][16 + d0 + r];
        }
        const float ra = 1.f / sa, rb = 1.f / sb;
        cxa0[r] *= ra; cxa1[r] *= ra; cxa2[r] *= ra; cxa3[r] *= ra;
        cxb0[r] *= rb; cxb1[r] *= rb; cxb2[r] *= rb; cxb3[r] *= rb;
    }

    // ============ mega-flush: each row one 8KB sequential run (P + zeros) ============
    const int kz = ntiles << 5;
    {
        #pragma unroll
        for (int rr4 = 0; rr4 < 4; ++rr4) {
            const int row = (wv << 2) + rr4;     // 0..31
            float s = 0.f;
            #pragma unroll
            for (int w = 0; w < 8; ++w) s += lbuf[w][row];
            const float rinv_r = 1.f / s;
            float* rowp = outSb + (size_t)(q0 + row) * S_LEN;
            const short* srow = &sstash[row * SSTR];
            for (int c = lane << 2; c < S_LEN; c += 256) {
                f32x4 v;
                if (c < kz) {
                    s16x4 sv = *(const s16x4*)(srow + c);
                    v[0] = bf2f(sv[0]) * rinv_r;
                    v[1] = bf2f(sv[1]) * rinv_r;
                    v[2] = bf2f(sv[2]) * rinv_r;
                    v[3] = bf2f(sv[3]) * rinv_r;
                } else {
                    v[0] = 0.f; v[1] = 0.f; v[2] = 0.f; v[3] = 0.f;
                }
                nt_store4(rowp + c, v);
            }
        }
    }

    // ============ ctx combine: 3-stage over 8 waves (reuse stash as [4][32][65]) ============
    __syncthreads();   // flush reads of stash complete
    {
        float* cb2 = (float*)smem;
        if (wv < 4) {
            const int base = wv * 2080;          // 32*65
            #pragma unroll
            for (int r = 0; r < 4; ++r) {
                cb2[base + (d0 + r) * 65 +  0 + l15] = cxa0[r];
                cb2[base + (d0 + r) * 65 + 16 + l15] = cxa1[r];
                cb2[base + (d0 + r) * 65 + 32 + l15] = cxa2[r];
                cb2[base + (d0 + r) * 65 + 48 + l15] = cxa3[r];
                cb2[base + (16 + d0 + r) * 65 +  0 + l15] = cxb0[r];
                cb2[base + (16 + d0 + r) * 65 + 16 + l15] = cxb1[r];
                cb2[base + (16 + d0 + r) * 65 + 32 + l15] = cxb2[r];
                cb2[base + (16 + d0 + r) * 65 + 48 + l15] = cxb3[r];
            }
        }
        __syncthreads();
        if (wv >= 4) {
            const int base = (wv - 4) * 2080;
            #pragma unroll
            for (int r = 0; r < 4; ++r) {
                cb2[base + (d0 + r) * 65 +  0 + l15] += cxa0[r];
                cb2[base + (d0 + r) * 65 + 16 + l15] += cxa1[r];
                cb2[base + (d0 + r) * 65 + 32 + l15] += cxa2[r];
                cb2[base + (d0 + r) * 65 + 48 + l15] += cxa3[r];
                cb2[base + (16 + d0 + r) * 65 +  0 + l15] += cxb0[r];
                cb2[base + (16 + d0 + r) * 65 + 16 + l15] += cxb1[r];
                cb2[base + (16 + d0 + r) * 65 + 32 + l15] += cxb2[r];
                cb2[base + (16 + d0 + r) * 65 + 48 + l15] += cxb3[r];
            }
        }
        __syncthreads();
        const int row = tid >> 4, dbase = (tid & 15) << 2;   // 32 rows x 16 thr (tid<512)
        if (tid < 512) {
            f32x4 acc = *(const f32x4*)&cb2[0 * 2080 + row * 65 + dbase];
            #pragma unroll
            for (int w = 1; w < 4; ++w) {
                f32x4 p = *(const f32x4*)&cb2[w * 2080 + row * 65 + dbase];
                acc[0] += p[0]; acc[1] += p[1]; acc[2] += p[2]; acc[3] += p[3];
            }
            *(f32x4*)(outCb + (size_t)(q0 + row) * D_K + dbase) = acc;
        }
    }
}

// ---------------- fallback (R0 kernel, proven) if ws too small ----------------
#define KSTRIDE 68
#define VSTRIDE 36
__global__ __launch_bounds__(256) void attn_causal_fb(
    const float* __restrict__ Q, const float* __restrict__ K,
    const float* __restrict__ V, float* __restrict__ outC,
    float* __restrict__ outS)
{
    __shared__ short Klds[32 * KSTRIDE];
    __shared__ short Vlds[64 * VSTRIDE];
    const int bh = blockIdx.x >> 5, q0 = (blockIdx.x & 31) << 6;
    const int tid = threadIdx.x, lane = tid & 63, wv = tid >> 6;
    const int q0w = q0 + (wv << 4), l15 = lane & 15, d0 = (lane >> 4) << 2;
    const int qg = q0w + l15, qhi = q0w + 15;
    const float* Kb = K + (size_t)bh * S_LEN * D_K;
    const float* Vb = V + (size_t)bh * S_LEN * D_K;
    float* outSb = outS + (size_t)bh * S_LEN * S_LEN;
    float* outCb = outC + (size_t)bh * S_LEN * D_K;
    s16x8 qf0, qf1;
    {
        const float4* qp = (const float4*)(Q + ((size_t)bh * S_LEN + qg) * D_K);
        qf0 = cat(cvt4(qp[d0 >> 2]), cvt4(qp[(d0 + 16) >> 2]));
        qf1 = cat(cvt4(qp[(d0 + 32) >> 2]), cvt4(qp[(d0 + 48) >> 2]));
    }
    const int npairs = (q0 >> 5) + 2;
    const float scale = 0.125f;
    float lsum = 0.f;
    for (int p = 0; p < npairs; ++p) {
        const int k0 = p << 5;
        for (int i = tid; i < 512; i += 256) {
            const int r = i >> 4, c = (i & 15) << 2;
            float4 f = *(const float4*)(Kb + (size_t)(k0 + r) * D_K + c);
            *(s16x4*)&Klds[r * KSTRIDE + c] = cvt4(f);
        }
        __syncthreads();
        if (k0 <= qhi) {
            #pragma unroll
            for (int s = 0; s < 2; ++s) {
                const short* kp = &Klds[(16 * s + l15) * KSTRIDE + d0];
                s16x8 a0 = cat(*(const s16x4*)kp, *(const s16x4*)(kp + 16));
                s16x8 a1 = cat(*(const s16x4*)(kp + 32), *(const s16x4*)(kp + 48));
                f32x4 c1 = {0.f,0.f,0.f,0.f};
                c1 = MFMA(a0, qf0, c1, 0,0,0);
                c1 = MFMA(a1, qf1, c1, 0,0,0);
                const int kbase = k0 + 16 * s + d0;
                #pragma unroll
                for (int r = 0; r < 4; ++r)
                    if (kbase + r <= qg) lsum += __expf(c1[r] * scale);
            }
        }
        __syncthreads();
    }
    lsum += __shfl_xor(lsum, 16);
    lsum += __shfl_xor(lsum, 32);
    const float rinv = 1.f / lsum;
    f32x4 ctx[4] = {{0,0,0,0},{0,0,0,0},{0,0,0,0},{0,0,0,0}};
    for (int p = 0; p < npairs; ++p) {
        const int k0 = p << 5;
        for (int i = tid; i < 512; i += 256) {
            const int r = i >> 4, c = (i & 15) << 2;
            float4 f = *(const float4*)(Kb + (size_t)(k0 + r) * D_K + c);
            *(s16x4*)&Klds[r * KSTRIDE + c] = cvt4(f);
            float4 gg = *(const float4*)(Vb + (size_t)(k0 + r) * D_K + c);
            Vlds[(c + 0) * VSTRIDE + r] = f2bf(gg.x);
            Vlds[(c + 1) * VSTRIDE + r] = f2bf(gg.y);
            Vlds[(c + 2) * VSTRIDE + r] = f2bf(gg.z);
            Vlds[(c + 3) * VSTRIDE + r] = f2bf(gg.w);
        }
        __syncthreads();
        if (k0 <= qhi) {
            s16x8 pf;
            #pragma unroll
            for (int s = 0; s < 2; ++s) {
                const short* kp = &Klds[(16 * s + l15) * KSTRIDE + d0];
                s16x8 a0 = cat(*(const s16x4*)kp, *(const s16x4*)(kp + 16));
                s16x8 a1 = cat(*(const s16x4*)(kp + 32), *(const s16x4*)(kp + 48));
                f32x4 c1 = {0.f,0.f,0.f,0.f};
                c1 = MFMA(a0, qf0, c1, 0,0,0);
                c1 = MFMA(a1, qf1, c1, 0,0,0);
                const int kbase = k0 + 16 * s + d0;
                f32x4 pw;
                #pragma unroll
                for (int r = 0; r < 4; ++r) {
                    float pe = (kbase + r <= qg) ? __expf(c1[r] * scale) * rinv : 0.f;
                    pw[r] = pe;
                    pf[4 * s + r] = f2bf(pe);
                }
                *(f32x4*)(outSb + (size_t)qg * S_LEN + kbase) = pw;
            }
            #pragma unroll
            for (int db = 0; db < 4; ++db) {
                const short* vp = &Vlds[(db * 16 + l15) * VSTRIDE + d0];
                s16x8 b = cat(*(const s16x4*)vp, *(const s16x4*)(vp + 16));
                ctx[db] = MFMA(pf, b, ctx[db], 0,0,0);
            }
        }
        __syncthreads();
    }
    #pragma unroll
    for (int db = 0; db < 4; ++db)
        #pragma unroll
        for (int r = 0; r < 4; ++r)
            outCb[(size_t)(q0w + d0 + r) * D_K + db * 16 + l15] = ctx[db][r];
    const int kz = ((qhi >> 5) + 1) << 5;
    const f32x4 z = {0.f,0.f,0.f,0.f};
    for (int r = 0; r < 16; ++r) {
        float* rowp = outSb + (size_t)(q0w + r) * S_LEN;
        for (int k = kz + (lane << 2); k < S_LEN; k += 256)
            *(f32x4*)(rowp + k) = z;
    }
}

extern "C" void kernel_launch(void* const* d_in, const int* in_sizes, int n_in,
                              void* d_out, int out_size, void* d_ws, size_t ws_size,
                              hipStream_t stream) {
    const float* Q = (const float*)d_in[0];
    const float* K = (const float*)d_in[1];
    const float* V = (const float*)d_in[2];
    float* outC = (float*)d_out;
    float* outS = (float*)d_out + (size_t)NBH * S_LEN * D_K;

    const size_t kb_elems = (size_t)NBH * S_LEN * D_K;
    const size_t vt_elems = (size_t)NBH * D_K * VT_STRIDE;
    const size_t need = (kb_elems + vt_elems) * sizeof(short);

    if (ws_size >= need) {
        short* Kb = (short*)d_ws;
        short* VT = Kb + kb_elems;
        preconv<<<dim3(NBH * 64), dim3(256), 0, stream>>>(K, V, Kb, VT);
        attn_sp8<<<dim3(2048), dim3(512), 0, stream>>>(Q, Kb, VT, outC, outS);
    } else {
        attn_causal_fb<<<dim3(1024), dim3(256), 0, stream>>>(Q, K, V, outC, outS);
    }
}